// Round 5
// baseline (219.974 us; speedup 1.0000x reference)
//
#include <hip/hip_runtime.h>
#include <hip/hip_bf16.h>
#include <math.h>

#define E_EDGES 1000000
#define E_TOT   2000000
#define N_NODES 50000
#define N_C     64
#define N_REL   8
#define NCOL    512     // bytes per Y row (fp8, 8 rel x 64)
#define NB      64      // dst buckets
#define BDIV    782     // ceil(50000/64); 49999/782 = 63
#define CH      2048    // edges per scatter block

typedef _Float16 half2v __attribute__((ext_vector_type(2)));
typedef _Float16 half8  __attribute__((ext_vector_type(8)));
typedef __attribute__((ext_vector_type(4))) float floatx4;
typedef __attribute__((ext_vector_type(2))) float floatx2;

static __device__ __forceinline__ unsigned short f2h_bits(float x) {
    _Float16 h = (_Float16)x;
    return __builtin_bit_cast(unsigned short, h);
}

static __device__ __forceinline__ unsigned pk4_fp8(float a, float b, float c, float d) {
    unsigned w = 0;
    w = __builtin_amdgcn_cvt_pk_fp8_f32(a, b, w, false);
    w = __builtin_amdgcn_cvt_pk_fp8_f32(c, d, w, true);
    return w;
}

static __device__ __forceinline__ float dot4_fp8(unsigned a, unsigned y, float acc) {
    floatx2 a0 = __builtin_amdgcn_cvt_pk_f32_fp8((int)a, false);
    floatx2 a1 = __builtin_amdgcn_cvt_pk_f32_fp8((int)a, true);
    floatx2 y0 = __builtin_amdgcn_cvt_pk_f32_fp8((int)y, false);
    floatx2 y1 = __builtin_amdgcn_cvt_pk_f32_fp8((int)y, true);
    acc = fmaf(a0.x, y0.x, acc);
    acc = fmaf(a0.y, y0.y, acc);
    acc = fmaf(a1.x, y1.x, acc);
    acc = fmaf(a1.y, y1.y, acc);
    return acc;
}

// fetch edge e of the concatenated pos+neg list
static __device__ __forceinline__ void get_edge(
    int e, const int* ei, const int* et, const int* nei, const int* net,
    int& s, int& d, int& r, int& neg)
{
    if (e < E_EDGES) {
        s = ei[e]; d = ei[E_EDGES + e]; r = et[e]; neg = 0;
    } else {
        int e2 = e - E_EDGES;
        s = nei[e2]; d = nei[E_EDGES + e2]; r = net[e2]; neg = 1;
    }
}

// Kernel 1: W -> f16; assignments -> f16 + fp8; zero d_out and gcount.
__global__ __launch_bounds__(256) void prep_kernel(
    const float* __restrict__ assign,
    const float* __restrict__ icl,
    const float* __restrict__ la,
    unsigned short* __restrict__ Wh,
    unsigned short* __restrict__ Ah,
    unsigned char*  __restrict__ A8,
    unsigned* __restrict__ gcount,
    float* __restrict__ out)
{
    int tid = blockIdx.x * blockDim.x + threadIdx.x;
    int nth = gridDim.x * blockDim.x;
    if (tid == 0) out[0] = 0.0f;
    if (tid < NB) gcount[tid] = 0u;

    for (int i = tid; i < N_REL * N_C * N_C; i += nth) {
        float w = 1.0f / (1.0f + __expf(-icl[i]));
        float g = 1.0f / (1.0f + __expf(-la[i])) * 1.2f - 0.1f;
        g = fminf(fmaxf(g, 0.0f), 1.0f);
        Wh[i] = f2h_bits(w * g);
    }

    const float4* a4 = (const float4*)assign;
    int n8 = N_NODES * N_C / 8;
    for (int i = tid; i < n8; i += nth) {
        float4 v0 = a4[2 * i], v1 = a4[2 * i + 1];
        ushort4 h0, h1;
        h0.x = f2h_bits(v0.x); h0.y = f2h_bits(v0.y);
        h0.z = f2h_bits(v0.z); h0.w = f2h_bits(v0.w);
        h1.x = f2h_bits(v1.x); h1.y = f2h_bits(v1.y);
        h1.z = f2h_bits(v1.z); h1.w = f2h_bits(v1.w);
        *(ushort4*)(Ah + 8 * i)     = h0;
        *(ushort4*)(Ah + 8 * i + 4) = h1;
        uint2 p;
        p.x = pk4_fp8(v0.x, v0.y, v0.z, v0.w);
        p.y = pk4_fp8(v1.x, v1.y, v1.z, v1.w);
        ((uint2*)A8)[i] = p;
    }
}

// Kernel 2: Y GEMM (f16 MFMA), epilogue -> fp8, coalesced 8B stores.
__global__ __launch_bounds__(256) void ygemm_kernel(
    const unsigned short* __restrict__ A,
    const unsigned short* __restrict__ W,
    unsigned char* __restrict__ Y8)
{
    __shared__ __align__(16) unsigned short lds[4][16 * 136];
    int wid  = threadIdx.x >> 6;
    int wave = blockIdx.x * 4 + wid;
    int lane = threadIdx.x & 63;
    if (wave >= N_NODES / 16) return;   // no __syncthreads here
    int r16 = lane & 15, quad = lane >> 4;

    const unsigned short* arow = A + (wave * 16 + r16) * N_C + quad * 8;
    half8 a0 = *(const half8*)(arow);
    half8 a1 = *(const half8*)(arow + 32);
    unsigned short* myl = lds[wid];

    for (int c = 0; c < 4; ++c) {
        #pragma unroll
        for (int t = 0; t < 8; ++t) {
            int col = (c * 8 + t) * 16 + r16;
            const unsigned short* brow = W + col * N_C + quad * 8;
            half8 b0 = *(const half8*)(brow);
            half8 b1 = *(const half8*)(brow + 32);
            floatx4 acc = {0.0f, 0.0f, 0.0f, 0.0f};
            acc = __builtin_amdgcn_mfma_f32_16x16x32_f16(a0, b0, acc, 0, 0, 0);
            acc = __builtin_amdgcn_mfma_f32_16x16x32_f16(a1, b1, acc, 0, 0, 0);
            #pragma unroll
            for (int reg = 0; reg < 4; ++reg)
                myl[(quad * 4 + reg) * 136 + t * 16 + r16] = f2h_bits(acc[reg]);
        }
        __asm__ volatile("s_waitcnt lgkmcnt(0)" ::: "memory");
        #pragma unroll
        for (int u = 0; u < 4; ++u) {
            int unit = u * 64 + lane;
            int row = unit >> 4, off = unit & 15;
            uint4 v = *(const uint4*)(myl + row * 136 + off * 8);
            half2v p0 = __builtin_bit_cast(half2v, v.x);
            half2v p1 = __builtin_bit_cast(half2v, v.y);
            half2v p2 = __builtin_bit_cast(half2v, v.z);
            half2v p3 = __builtin_bit_cast(half2v, v.w);
            uint2 o;
            o.x = pk4_fp8((float)p0[0], (float)p0[1], (float)p1[0], (float)p1[1]);
            o.y = pk4_fp8((float)p2[0], (float)p2[1], (float)p3[0], (float)p3[1]);
            *(uint2*)(Y8 + (size_t)(wave * 16 + row) * NCOL + c * 128 + off * 8) = o;
        }
        __asm__ volatile("s_waitcnt lgkmcnt(0)" ::: "memory");
    }
}

// Kernel 3: bucket histogram over dst
__global__ __launch_bounds__(256) void hist_kernel(
    const int* __restrict__ ei, const int* __restrict__ nei,
    unsigned* __restrict__ gcount)
{
    __shared__ unsigned lh[NB];
    if (threadIdx.x < NB) lh[threadIdx.x] = 0u;
    __syncthreads();
    int tid = blockIdx.x * blockDim.x + threadIdx.x;
    int nth = gridDim.x * blockDim.x;
    for (int e = tid; e < E_TOT; e += nth) {
        int d = (e < E_EDGES) ? ei[E_EDGES + e] : nei[e];  // nei[1M + (e-1M)]
        atomicAdd(&lh[(unsigned)d / BDIV], 1u);
    }
    __syncthreads();
    if (threadIdx.x < NB) atomicAdd(&gcount[threadIdx.x], lh[threadIdx.x]);
}

// Kernel 4: exclusive prefix (one wave)
__global__ __launch_bounds__(64) void prefix_kernel(
    const unsigned* __restrict__ gcount,
    unsigned* __restrict__ gstart,
    unsigned* __restrict__ gcursor)
{
    int lane = threadIdx.x;
    unsigned cnt = gcount[lane];
    unsigned sum = cnt;
    #pragma unroll
    for (int off = 1; off < 64; off <<= 1) {
        unsigned v = __shfl_up(sum, off);
        if (lane >= off) sum += v;
    }
    gstart[lane + 1] = sum;            // inclusive
    if (lane == 0) gstart[0] = 0u;
    gcursor[lane] = sum - cnt;         // exclusive
}

// Kernel 5: scatter edges into buckets as packed 8B records
__global__ __launch_bounds__(256) void scatter_kernel(
    const int* __restrict__ ei, const int* __restrict__ et,
    const int* __restrict__ nei, const int* __restrict__ net,
    unsigned* __restrict__ gcursor,
    uint2* __restrict__ binned)
{
    __shared__ unsigned llo[CH];
    __shared__ unsigned prk[CH];      // rank | (hi<<12)
    __shared__ unsigned lhist[NB];
    __shared__ unsigned lbase[NB];
    if (threadIdx.x < NB) lhist[threadIdx.x] = 0u;
    __syncthreads();

    int base = blockIdx.x * CH;
    #pragma unroll
    for (int i = 0; i < CH / 256; ++i) {
        int idx = i * 256 + threadIdx.x;
        int e = base + idx;
        if (e < E_TOT) {
            int s, d, r, neg;
            get_edge(e, ei, et, nei, net, s, d, r, neg);
            unsigned b = (unsigned)d / BDIV;
            unsigned rank = atomicAdd(&lhist[b], 1u);
            llo[idx] = (unsigned)s | ((unsigned)d << 16);
            prk[idx] = rank | ((unsigned)(r | (neg << 3)) << 12);
        }
    }
    __syncthreads();
    if (threadIdx.x < NB)
        lbase[threadIdx.x] = atomicAdd(&gcursor[threadIdx.x], lhist[threadIdx.x]);
    __syncthreads();
    #pragma unroll
    for (int i = 0; i < CH / 256; ++i) {
        int idx = i * 256 + threadIdx.x;
        int e = base + idx;
        if (e < E_TOT) {
            unsigned lo = llo[idx];
            unsigned p  = prk[idx];
            unsigned b  = (lo >> 16) / BDIV;
            uint2 rec; rec.x = lo; rec.y = p >> 12;   // hi = rel | neg<<3
            binned[lbase[b] + (p & 0xFFFu)] = rec;
        }
    }
}

// Kernel 6: XCD-pinned edge pass. Class x = blockIdx%8 handles buckets b%8==x.
__global__ __launch_bounds__(256, 8) void edge_kernel(
    const unsigned char* __restrict__ A8,
    const unsigned char* __restrict__ Y8,
    const float* __restrict__ absent_bias,
    const uint2* __restrict__ binned,
    const unsigned* __restrict__ gstart,
    float* __restrict__ out)
{
    __shared__ float bias_s[N_REL];
    if (threadIdx.x < N_REL) bias_s[threadIdx.x] = absent_bias[threadIdx.x];
    __syncthreads();

    int x    = blockIdx.x & 7;           // XCD class
    int slot = blockIdx.x >> 3;
    int nslot = gridDim.x >> 3;
    int l     = threadIdx.x & 3;         // lane within edge
    int group = threadIdx.x >> 2;        // 0..63

    float acc = 0.0f;
    #pragma unroll
    for (int bi = 0; bi < NB / 8; ++bi) {
        int b = x + bi * 8;
        unsigned lo = gstart[b], hi = gstart[b + 1];
        for (unsigned i = lo + slot * 64 + group; i < hi; i += nslot * 64) {
            uint2 rec = binned[i];
            int s = rec.x & 0xFFFF;
            int d = rec.x >> 16;
            int r = rec.y & 7;
            int neg = rec.y >> 3;
            uint4 av = *(const uint4*)(A8 + (size_t)s * N_C  + l * 16);
            uint4 yv = *(const uint4*)(Y8 + (size_t)d * NCOL + r * N_C + l * 16);
            float dot = 0.0f;
            dot = dot4_fp8(av.x, yv.x, dot);
            dot = dot4_fp8(av.y, yv.y, dot);
            dot = dot4_fp8(av.z, yv.z, dot);
            dot = dot4_fp8(av.w, yv.w, dot);
            dot += __shfl_xor(dot, 1);
            dot += __shfl_xor(dot, 2);
            if (l == 0) {
                float xv = dot + bias_s[r];
                xv = neg ? xv : -xv;
                acc += fmaxf(xv, 0.0f) + __logf(1.0f + __expf(-fabsf(xv)));
            }
        }
    }

    acc += __shfl_xor(acc, 1);
    acc += __shfl_xor(acc, 2);
    acc += __shfl_xor(acc, 4);
    acc += __shfl_xor(acc, 8);
    acc += __shfl_xor(acc, 16);
    acc += __shfl_xor(acc, 32);
    __shared__ float red[4];
    if ((threadIdx.x & 63) == 0) red[threadIdx.x >> 6] = acc;
    __syncthreads();
    if (threadIdx.x == 0)
        atomicAdd(out, (red[0] + red[1] + red[2] + red[3]) * (1.0f / (float)E_EDGES));
}

extern "C" void kernel_launch(void* const* d_in, const int* in_sizes, int n_in,
                              void* d_out, int out_size, void* d_ws, size_t ws_size,
                              hipStream_t stream) {
    const float* assign = (const float*)d_in[0];
    const float* icl    = (const float*)d_in[1];
    const float* la     = (const float*)d_in[2];
    const float* ab     = (const float*)d_in[3];
    const int*   ei     = (const int*)d_in[4];
    const int*   et     = (const int*)d_in[5];
    const int*   nei    = (const int*)d_in[6];
    const int*   net    = (const int*)d_in[7];
    float* out = (float*)d_out;

    char* base = (char*)d_ws;
    size_t off = 0;
    unsigned short* Wh = (unsigned short*)(base + off); off += 65536;
    unsigned short* Ah = (unsigned short*)(base + off); off += (size_t)N_NODES * N_C * 2;
    unsigned char*  A8 = (unsigned char*) (base + off); off += (size_t)N_NODES * N_C;
    unsigned char*  Y8 = (unsigned char*) (base + off); off += (size_t)N_NODES * NCOL;
    uint2*      binned = (uint2*)         (base + off); off += (size_t)E_TOT * 8;
    unsigned*   gcount = (unsigned*)      (base + off); off += 256;
    unsigned*   gstart = (unsigned*)      (base + off); off += 512;
    unsigned*  gcursor = (unsigned*)      (base + off); off += 256;

    prep_kernel<<<1024, 256, 0, stream>>>(assign, icl, la, Wh, Ah, A8, gcount, out);
    ygemm_kernel<<<(N_NODES / 16 + 3) / 4, 256, 0, stream>>>(Ah, Wh, Y8);
    hist_kernel<<<1024, 256, 0, stream>>>(ei, nei, gcount);
    prefix_kernel<<<1, 64, 0, stream>>>(gcount, gstart, gcursor);
    scatter_kernel<<<(E_TOT + CH - 1) / CH, 256, 0, stream>>>(ei, et, nei, net, gcursor, binned);
    edge_kernel<<<2048, 256, 0, stream>>>(A8, Y8, ab, binned, gstart, out);
}

// Round 6
// 198.740 us; speedup vs baseline: 1.1068x; 1.1068x over previous
//
#include <hip/hip_runtime.h>
#include <hip/hip_bf16.h>
#include <math.h>

#define E_EDGES 1000000
#define E_TOT   2000000
#define N_NODES 50000
#define N_C     64
#define N_REL   8
#define NCOL    512     // bytes per Y row (fp8, 8 rel x 64)
#define NB      64      // dst buckets
#define BDIV    782     // ceil(50000/64)
#define CAPLG   15      // bucket capacity 32768 (expected 31280, sigma ~175)
#define CH      2048    // edges per scatter chunk

typedef _Float16 half2v __attribute__((ext_vector_type(2)));
typedef _Float16 half8  __attribute__((ext_vector_type(8)));
typedef __attribute__((ext_vector_type(4))) float floatx4;
typedef __attribute__((ext_vector_type(2))) float floatx2;

static __device__ __forceinline__ unsigned short f2h_bits(float x) {
    _Float16 h = (_Float16)x;
    return __builtin_bit_cast(unsigned short, h);
}

static __device__ __forceinline__ unsigned pk4_fp8(float a, float b, float c, float d) {
    unsigned w = 0;
    w = __builtin_amdgcn_cvt_pk_fp8_f32(a, b, w, false);
    w = __builtin_amdgcn_cvt_pk_fp8_f32(c, d, w, true);
    return w;
}

static __device__ __forceinline__ float dot4_fp8(unsigned a, unsigned y, float acc) {
    floatx2 a0 = __builtin_amdgcn_cvt_pk_f32_fp8((int)a, false);
    floatx2 a1 = __builtin_amdgcn_cvt_pk_f32_fp8((int)a, true);
    floatx2 y0 = __builtin_amdgcn_cvt_pk_f32_fp8((int)y, false);
    floatx2 y1 = __builtin_amdgcn_cvt_pk_f32_fp8((int)y, true);
    acc = fmaf(a0.x, y0.x, acc);
    acc = fmaf(a0.y, y0.y, acc);
    acc = fmaf(a1.x, y1.x, acc);
    acc = fmaf(a1.y, y1.y, acc);
    return acc;
}

static __device__ __forceinline__ void get_edge(
    int e, const int* ei, const int* et, const int* nei, const int* net,
    int& s, int& d, int& r, int& neg)
{
    if (e < E_EDGES) {
        s = ei[e]; d = ei[E_EDGES + e]; r = et[e]; neg = 0;
    } else {
        int e2 = e - E_EDGES;
        s = nei[e2]; d = nei[E_EDGES + e2]; r = net[e2]; neg = 1;
    }
}

// Kernel 1 (fused): W -> f16; assignments -> fp8; scatter edges into
// fixed-capacity dst buckets as packed 8B records.
__global__ __launch_bounds__(256) void prep_scatter_kernel(
    const float* __restrict__ assign,
    const float* __restrict__ icl,
    const float* __restrict__ la,
    const int* __restrict__ ei, const int* __restrict__ et,
    const int* __restrict__ nei, const int* __restrict__ net,
    unsigned short* __restrict__ Wh,
    unsigned char*  __restrict__ A8,
    unsigned* __restrict__ gcursor,   // pre-zeroed, holds bucket counts after
    uint2* __restrict__ binned)
{
    __shared__ unsigned llo[CH];
    __shared__ unsigned prk[CH];      // rank | (rel|neg<<3)<<12
    __shared__ unsigned lhist[NB];
    __shared__ unsigned lbase[NB];
    if (threadIdx.x < NB) lhist[threadIdx.x] = 0u;

    int tid = blockIdx.x * blockDim.x + threadIdx.x;
    int nth = gridDim.x * blockDim.x;

    for (int i = tid; i < N_REL * N_C * N_C; i += nth) {
        float w = 1.0f / (1.0f + __expf(-icl[i]));
        float g = 1.0f / (1.0f + __expf(-la[i])) * 1.2f - 0.1f;
        g = fminf(fmaxf(g, 0.0f), 1.0f);
        Wh[i] = f2h_bits(w * g);
    }

    const float4* a4 = (const float4*)assign;
    int n16 = N_NODES * N_C / 16;
    for (int i = tid; i < n16; i += nth) {
        float4 v0 = a4[4 * i], v1 = a4[4 * i + 1], v2 = a4[4 * i + 2], v3 = a4[4 * i + 3];
        uint4 p;
        p.x = pk4_fp8(v0.x, v0.y, v0.z, v0.w);
        p.y = pk4_fp8(v1.x, v1.y, v1.z, v1.w);
        p.z = pk4_fp8(v2.x, v2.y, v2.z, v2.w);
        p.w = pk4_fp8(v3.x, v3.y, v3.z, v3.w);
        ((uint4*)A8)[i] = p;
    }

    __syncthreads();
    int base = blockIdx.x * CH;
    #pragma unroll
    for (int i = 0; i < CH / 256; ++i) {
        int idx = i * 256 + threadIdx.x;
        int e = base + idx;
        if (e < E_TOT) {
            int s, d, r, neg;
            get_edge(e, ei, et, nei, net, s, d, r, neg);
            unsigned b = (unsigned)d / BDIV;
            unsigned rank = atomicAdd(&lhist[b], 1u);
            llo[idx] = (unsigned)s | ((unsigned)d << 16);
            prk[idx] = rank | ((unsigned)(r | (neg << 3)) << 12);
        }
    }
    __syncthreads();
    if (threadIdx.x < NB)
        lbase[threadIdx.x] = atomicAdd(&gcursor[threadIdx.x], lhist[threadIdx.x]);
    __syncthreads();
    #pragma unroll
    for (int i = 0; i < CH / 256; ++i) {
        int idx = i * 256 + threadIdx.x;
        int e = base + idx;
        if (e < E_TOT) {
            unsigned lo = llo[idx];
            unsigned p  = prk[idx];
            unsigned b  = (lo >> 16) / BDIV;
            unsigned posr = lbase[b] + (p & 0xFFFu);   // rank within bucket
            if (posr < (1u << CAPLG)) {                // guard (never trips)
                uint2 rec; rec.x = lo; rec.y = p >> 12;
                binned[((unsigned)b << CAPLG) + posr] = rec;
            }
        }
    }
}

// Kernel 2: Y GEMM (f16 MFMA, fragments converted from fp32 in-register),
// epilogue -> fp8, coalesced 8B stores via LDS repack.
__global__ __launch_bounds__(256) void ygemm_kernel(
    const float* __restrict__ assign,
    const unsigned short* __restrict__ W,
    unsigned char* __restrict__ Y8)
{
    __shared__ __align__(16) unsigned short lds[4][16 * 136];
    int wid  = threadIdx.x >> 6;
    int wave = blockIdx.x * 4 + wid;
    int lane = threadIdx.x & 63;
    if (wave >= N_NODES / 16) return;   // no __syncthreads here
    int r16 = lane & 15, quad = lane >> 4;

    const float* ar = assign + (wave * 16 + r16) * N_C + quad * 8;
    float4 f0 = *(const float4*)(ar);
    float4 f1 = *(const float4*)(ar + 4);
    float4 f2 = *(const float4*)(ar + 32);
    float4 f3 = *(const float4*)(ar + 36);
    half8 a0, a1;
    a0[0]=(_Float16)f0.x; a0[1]=(_Float16)f0.y; a0[2]=(_Float16)f0.z; a0[3]=(_Float16)f0.w;
    a0[4]=(_Float16)f1.x; a0[5]=(_Float16)f1.y; a0[6]=(_Float16)f1.z; a0[7]=(_Float16)f1.w;
    a1[0]=(_Float16)f2.x; a1[1]=(_Float16)f2.y; a1[2]=(_Float16)f2.z; a1[3]=(_Float16)f2.w;
    a1[4]=(_Float16)f3.x; a1[5]=(_Float16)f3.y; a1[6]=(_Float16)f3.z; a1[7]=(_Float16)f3.w;
    unsigned short* myl = lds[wid];

    for (int c = 0; c < 4; ++c) {
        #pragma unroll
        for (int t = 0; t < 8; ++t) {
            int col = (c * 8 + t) * 16 + r16;
            const unsigned short* brow = W + col * N_C + quad * 8;
            half8 b0 = *(const half8*)(brow);
            half8 b1 = *(const half8*)(brow + 32);
            floatx4 acc = {0.0f, 0.0f, 0.0f, 0.0f};
            acc = __builtin_amdgcn_mfma_f32_16x16x32_f16(a0, b0, acc, 0, 0, 0);
            acc = __builtin_amdgcn_mfma_f32_16x16x32_f16(a1, b1, acc, 0, 0, 0);
            #pragma unroll
            for (int reg = 0; reg < 4; ++reg)
                myl[(quad * 4 + reg) * 136 + t * 16 + r16] = f2h_bits(acc[reg]);
        }
        __asm__ volatile("s_waitcnt lgkmcnt(0)" ::: "memory");
        #pragma unroll
        for (int u = 0; u < 4; ++u) {
            int unit = u * 64 + lane;
            int row = unit >> 4, off = unit & 15;
            uint4 v = *(const uint4*)(myl + row * 136 + off * 8);
            half2v p0 = __builtin_bit_cast(half2v, v.x);
            half2v p1 = __builtin_bit_cast(half2v, v.y);
            half2v p2 = __builtin_bit_cast(half2v, v.z);
            half2v p3 = __builtin_bit_cast(half2v, v.w);
            uint2 o;
            o.x = pk4_fp8((float)p0[0], (float)p0[1], (float)p1[0], (float)p1[1]);
            o.y = pk4_fp8((float)p2[0], (float)p2[1], (float)p3[0], (float)p3[1]);
            *(uint2*)(Y8 + (size_t)(wave * 16 + row) * NCOL + c * 128 + off * 8) = o;
        }
        __asm__ volatile("s_waitcnt lgkmcnt(0)" ::: "memory");
    }
}

// Kernel 3: XCD-pinned edge pass, unrolled x2 for memory-level parallelism.
__global__ __launch_bounds__(256, 8) void edge_kernel(
    const unsigned char* __restrict__ A8,
    const unsigned char* __restrict__ Y8,
    const float* __restrict__ absent_bias,
    const uint2* __restrict__ binned,
    const unsigned* __restrict__ gcursor,
    float* __restrict__ out)
{
    __shared__ float bias_s[N_REL];
    if (threadIdx.x < N_REL) bias_s[threadIdx.x] = absent_bias[threadIdx.x];
    __syncthreads();

    int x     = blockIdx.x & 7;          // XCD class
    int slot  = blockIdx.x >> 3;
    int nslot = gridDim.x >> 3;
    int l     = threadIdx.x & 3;
    int group = threadIdx.x >> 2;        // 0..63
    unsigned str = (unsigned)nslot * 64;

    float acc = 0.0f;
    #pragma unroll
    for (int bi = 0; bi < NB / 8; ++bi) {
        int b = x + bi * 8;
        unsigned lo = (unsigned)b << CAPLG;
        unsigned hi = lo + gcursor[b];
        unsigned i = lo + slot * 64 + group;
        for (; i + str < hi; i += 2 * str) {
            uint2 rec0 = binned[i];
            uint2 rec1 = binned[i + str];
            int s0 = rec0.x & 0xFFFF, d0 = rec0.x >> 16, r0 = rec0.y & 7, n0 = rec0.y >> 3;
            int s1 = rec1.x & 0xFFFF, d1 = rec1.x >> 16, r1 = rec1.y & 7, n1 = rec1.y >> 3;
            uint4 av0 = *(const uint4*)(A8 + (size_t)s0 * N_C  + l * 16);
            uint4 yv0 = *(const uint4*)(Y8 + (size_t)d0 * NCOL + r0 * N_C + l * 16);
            uint4 av1 = *(const uint4*)(A8 + (size_t)s1 * N_C  + l * 16);
            uint4 yv1 = *(const uint4*)(Y8 + (size_t)d1 * NCOL + r1 * N_C + l * 16);
            float dot0 = 0.0f, dot1 = 0.0f;
            dot0 = dot4_fp8(av0.x, yv0.x, dot0); dot1 = dot4_fp8(av1.x, yv1.x, dot1);
            dot0 = dot4_fp8(av0.y, yv0.y, dot0); dot1 = dot4_fp8(av1.y, yv1.y, dot1);
            dot0 = dot4_fp8(av0.z, yv0.z, dot0); dot1 = dot4_fp8(av1.z, yv1.z, dot1);
            dot0 = dot4_fp8(av0.w, yv0.w, dot0); dot1 = dot4_fp8(av1.w, yv1.w, dot1);
            dot0 += __shfl_xor(dot0, 1); dot1 += __shfl_xor(dot1, 1);
            dot0 += __shfl_xor(dot0, 2); dot1 += __shfl_xor(dot1, 2);
            if (l == 0) {
                float x0 = dot0 + bias_s[r0]; x0 = n0 ? x0 : -x0;
                float x1 = dot1 + bias_s[r1]; x1 = n1 ? x1 : -x1;
                acc += fmaxf(x0, 0.0f) + __logf(1.0f + __expf(-fabsf(x0)));
                acc += fmaxf(x1, 0.0f) + __logf(1.0f + __expf(-fabsf(x1)));
            }
        }
        if (i < hi) {
            uint2 rec = binned[i];
            int s = rec.x & 0xFFFF, d = rec.x >> 16, r = rec.y & 7, neg = rec.y >> 3;
            uint4 av = *(const uint4*)(A8 + (size_t)s * N_C  + l * 16);
            uint4 yv = *(const uint4*)(Y8 + (size_t)d * NCOL + r * N_C + l * 16);
            float dot = 0.0f;
            dot = dot4_fp8(av.x, yv.x, dot);
            dot = dot4_fp8(av.y, yv.y, dot);
            dot = dot4_fp8(av.z, yv.z, dot);
            dot = dot4_fp8(av.w, yv.w, dot);
            dot += __shfl_xor(dot, 1);
            dot += __shfl_xor(dot, 2);
            if (l == 0) {
                float xv = dot + bias_s[r]; xv = neg ? xv : -xv;
                acc += fmaxf(xv, 0.0f) + __logf(1.0f + __expf(-fabsf(xv)));
            }
        }
    }

    acc += __shfl_xor(acc, 1);
    acc += __shfl_xor(acc, 2);
    acc += __shfl_xor(acc, 4);
    acc += __shfl_xor(acc, 8);
    acc += __shfl_xor(acc, 16);
    acc += __shfl_xor(acc, 32);
    __shared__ float red[4];
    if ((threadIdx.x & 63) == 0) red[threadIdx.x >> 6] = acc;
    __syncthreads();
    if (threadIdx.x == 0)
        atomicAdd(out, (red[0] + red[1] + red[2] + red[3]) * (1.0f / (float)E_EDGES));
}

extern "C" void kernel_launch(void* const* d_in, const int* in_sizes, int n_in,
                              void* d_out, int out_size, void* d_ws, size_t ws_size,
                              hipStream_t stream) {
    const float* assign = (const float*)d_in[0];
    const float* icl    = (const float*)d_in[1];
    const float* la     = (const float*)d_in[2];
    const float* ab     = (const float*)d_in[3];
    const int*   ei     = (const int*)d_in[4];
    const int*   et     = (const int*)d_in[5];
    const int*   nei    = (const int*)d_in[6];
    const int*   net    = (const int*)d_in[7];
    float* out = (float*)d_out;

    char* base = (char*)d_ws;
    size_t off = 0;
    unsigned short* Wh = (unsigned short*)(base + off); off += 65536;
    unsigned char*  A8 = (unsigned char*) (base + off); off += (size_t)N_NODES * N_C;
    unsigned char*  Y8 = (unsigned char*) (base + off); off += (size_t)N_NODES * NCOL;
    uint2*      binned = (uint2*)         (base + off); off += (size_t)NB * (1u << CAPLG) * 8;
    unsigned*  gcursor = (unsigned*)      (base + off); off += 256;

    hipMemsetAsync(gcursor, 0, NB * sizeof(unsigned), stream);
    hipMemsetAsync(out, 0, sizeof(float), stream);

    prep_scatter_kernel<<<(E_TOT + CH - 1) / CH, 256, 0, stream>>>(
        assign, icl, la, ei, et, nei, net, Wh, A8, gcursor, binned);
    ygemm_kernel<<<(N_NODES / 16 + 3) / 4, 256, 0, stream>>>(assign, Wh, Y8);
    edge_kernel<<<2048, 256, 0, stream>>>(A8, Y8, ab, binned, gcursor, out);
}

// Round 8
// 182.048 us; speedup vs baseline: 1.2083x; 1.0917x over previous
//
#include <hip/hip_runtime.h>
#include <hip/hip_bf16.h>
#include <math.h>

#define E_EDGES 1000000
#define N_NODES 50000
#define N_C     64
#define N_REL   8
#define CHB     2048        // edges per block
#define CAP     384         // per-relation LDS list capacity (E=256, 8.5 sigma)
#define NBLK    489         // ceil(1e6 / 2048)

typedef _Float16 half2v __attribute__((ext_vector_type(2)));
typedef _Float16 half8  __attribute__((ext_vector_type(8)));
typedef __attribute__((ext_vector_type(4))) float floatx4;
typedef __attribute__((ext_vector_type(2))) float floatx2;

static __device__ __forceinline__ unsigned short f2h_bits(float x) {
    _Float16 h = (_Float16)x;
    return __builtin_bit_cast(unsigned short, h);
}

// pack 4 fp32 -> 4 fp8 e4m3 (RNE), byte j = element j
static __device__ __forceinline__ unsigned pk4_fp8(float a, float b, float c, float d) {
    unsigned w = 0;
    w = __builtin_amdgcn_cvt_pk_fp8_f32(a, b, w, false);
    w = __builtin_amdgcn_cvt_pk_fp8_f32(c, d, w, true);
    return w;
}

// decode 8 fp8 bytes -> half8 (fp8 values are exact in f16, so pkrtz is exact)
static __device__ __forceinline__ half8 fp8x8_h8(uint2 v) {
    floatx2 f0 = __builtin_amdgcn_cvt_pk_f32_fp8((int)v.x, false);
    floatx2 f1 = __builtin_amdgcn_cvt_pk_f32_fp8((int)v.x, true);
    floatx2 f2 = __builtin_amdgcn_cvt_pk_f32_fp8((int)v.y, false);
    floatx2 f3 = __builtin_amdgcn_cvt_pk_f32_fp8((int)v.y, true);
    half2v h0 = __builtin_bit_cast(half2v, __builtin_amdgcn_cvt_pkrtz(f0.x, f0.y));
    half2v h1 = __builtin_bit_cast(half2v, __builtin_amdgcn_cvt_pkrtz(f1.x, f1.y));
    half2v h2 = __builtin_bit_cast(half2v, __builtin_amdgcn_cvt_pkrtz(f2.x, f2.y));
    half2v h3 = __builtin_bit_cast(half2v, __builtin_amdgcn_cvt_pkrtz(f3.x, f3.y));
    half8 h;
    h[0] = h0[0]; h[1] = h0[1]; h[2] = h1[0]; h[3] = h1[1];
    h[4] = h2[0]; h[5] = h2[1]; h[6] = h3[0]; h[7] = h3[1];
    return h;
}

// Kernel 1: W = sigmoid(icl)*gate -> f16 [512][64] row-major (row = r*64+outdim);
// assignments fp32 -> fp8 A8 [50000][64].
__global__ __launch_bounds__(256) void prep_kernel(
    const float* __restrict__ assign,
    const float* __restrict__ icl,
    const float* __restrict__ la,
    unsigned short* __restrict__ Wh,
    unsigned char*  __restrict__ A8)
{
    int tid = blockIdx.x * blockDim.x + threadIdx.x;
    int nth = gridDim.x * blockDim.x;

    for (int i = tid; i < N_REL * N_C * N_C; i += nth) {
        float w = 1.0f / (1.0f + __expf(-icl[i]));
        float g = 1.0f / (1.0f + __expf(-la[i])) * 1.2f - 0.1f;
        g = fminf(fmaxf(g, 0.0f), 1.0f);
        Wh[i] = f2h_bits(w * g);
    }

    const float4* a4 = (const float4*)assign;
    int n16 = N_NODES * N_C / 16;
    for (int i = tid; i < n16; i += nth) {
        float4 v0 = a4[4 * i], v1 = a4[4 * i + 1], v2 = a4[4 * i + 2], v3 = a4[4 * i + 3];
        uint4 p;
        p.x = pk4_fp8(v0.x, v0.y, v0.z, v0.w);
        p.y = pk4_fp8(v1.x, v1.y, v1.z, v1.w);
        p.z = pk4_fp8(v2.x, v2.y, v2.z, v2.w);
        p.w = pk4_fp8(v3.x, v3.y, v3.z, v3.w);
        ((uint4*)A8)[i] = p;
    }
}

// Kernel 2: fused edge pass. Each block: read 2048 edges sequentially, bin by
// relation in LDS, then per relation MFMA-batch 16 edges/wave:
//   P[64 x 16] = W_r (A-op, stationary) x dst-vecs (B-op, fp8 gather -> f16)
//   logit_n = sum_m src[m][n] * P[m][n]  (fp8 src dword gathers vs f32 accs)
// Fragment layout identical to the verified ygemm usage.
__global__ __launch_bounds__(256, 4) void edge_kernel(
    const unsigned char* __restrict__ A8,
    const unsigned short* __restrict__ Wh,
    const float* __restrict__ absent_bias,
    const int* __restrict__ ei, const int* __restrict__ et,
    const int* __restrict__ nei, const int* __restrict__ net,
    float* __restrict__ out)
{
    __shared__ unsigned list[N_REL * CAP];
    __shared__ unsigned cnt[N_REL];
    __shared__ float red[4];
    if (threadIdx.x < N_REL) cnt[threadIdx.x] = 0u;
    __syncthreads();

    int blk = blockIdx.x;
    bool isneg = blk >= NBLK;
    int lb = isneg ? blk - NBLK : blk;
    const int* Es = isneg ? nei : ei;
    const int* Et = isneg ? net : et;
    float sign = isneg ? 1.0f : -1.0f;
    int base = lb * CHB;
    int elim = min(base + CHB, E_EDGES);

    // Phase 1: LDS relation binning (coalesced edge reads)
    for (int e = base + threadIdx.x; e < elim; e += 256) {
        int s = Es[e];
        int d = Es[E_EDGES + e];
        int r = Et[e];
        unsigned rank = atomicAdd(&cnt[r], 1u);
        if (rank < CAP) list[r * CAP + rank] = (unsigned)s | ((unsigned)d << 16);
    }
    __syncthreads();

    int lane = threadIdx.x & 63;
    int wid  = threadIdx.x >> 6;
    int n16  = lane & 15;
    int quad = lane >> 4;
    float loss = 0.0f;

    for (int r = 0; r < N_REL; ++r) {
        int n_r = min((int)cnt[r], CAP);
        if (n_r == 0) continue;
        float bias = absent_bias[r];
        // stationary A-operand: W_r rows (out-dim tile mt, k-tile kt)
        half8 wf[4][2];
        #pragma unroll
        for (int mt = 0; mt < 4; ++mt)
            #pragma unroll
            for (int kt = 0; kt < 2; ++kt)
                wf[mt][kt] = *(const half8*)(Wh + ((r * 64 + mt * 16 + n16) << 6) + kt * 32 + quad * 8);

        for (int g = wid; g * 16 < n_r; g += 4) {
            int idx = g * 16 + n16;
            bool valid = idx < n_r;
            unsigned rec = list[r * CAP + (valid ? idx : 0)];
            int src = rec & 0xFFFF;
            int dst = rec >> 16;
            // B-operand: dst vector, k = kt*32 + quad*8 + j  (8B fp8 -> f16)
            const unsigned char* drow = A8 + ((size_t)dst << 6) + quad * 8;
            half8 b0 = fp8x8_h8(*(const uint2*)(drow));
            half8 b1 = fp8x8_h8(*(const uint2*)(drow + 32));
            floatx4 ac[4];
            #pragma unroll
            for (int mt = 0; mt < 4; ++mt) {
                floatx4 z = {0.0f, 0.0f, 0.0f, 0.0f};
                z = __builtin_amdgcn_mfma_f32_16x16x32_f16(wf[mt][0], b0, z, 0, 0, 0);
                ac[mt] = __builtin_amdgcn_mfma_f32_16x16x32_f16(wf[mt][1], b1, z, 0, 0, 0);
            }
            // src dot: lane holds P[m = mt*16 + quad*4 + reg][n]; src byte m matches
            const unsigned char* srow = A8 + ((size_t)src << 6) + quad * 4;
            float dot = 0.0f;
            #pragma unroll
            for (int mt = 0; mt < 4; ++mt) {
                unsigned gw = *(const unsigned*)(srow + mt * 16);
                floatx2 lo = __builtin_amdgcn_cvt_pk_f32_fp8((int)gw, false);
                floatx2 hi = __builtin_amdgcn_cvt_pk_f32_fp8((int)gw, true);
                dot = fmaf(lo.x, ac[mt][0], dot);
                dot = fmaf(lo.y, ac[mt][1], dot);
                dot = fmaf(hi.x, ac[mt][2], dot);
                dot = fmaf(hi.y, ac[mt][3], dot);
            }
            dot += __shfl_xor(dot, 16);
            dot += __shfl_xor(dot, 32);
            if (quad == 0 && valid) {
                float x = sign * (dot + bias);
                loss += fmaxf(x, 0.0f) + __logf(1.0f + __expf(-fabsf(x)));
            }
        }
    }

    loss += __shfl_xor(loss, 1);
    loss += __shfl_xor(loss, 2);
    loss += __shfl_xor(loss, 4);
    loss += __shfl_xor(loss, 8);
    loss += __shfl_xor(loss, 16);
    loss += __shfl_xor(loss, 32);
    if (lane == 0) red[wid] = loss;
    __syncthreads();
    if (threadIdx.x == 0)
        atomicAdd(out, (red[0] + red[1] + red[2] + red[3]) * (1.0f / (float)E_EDGES));
}

extern "C" void kernel_launch(void* const* d_in, const int* in_sizes, int n_in,
                              void* d_out, int out_size, void* d_ws, size_t ws_size,
                              hipStream_t stream) {
    const float* assign = (const float*)d_in[0];
    const float* icl    = (const float*)d_in[1];
    const float* la     = (const float*)d_in[2];
    const float* ab     = (const float*)d_in[3];
    const int*   ei     = (const int*)d_in[4];
    const int*   et     = (const int*)d_in[5];
    const int*   nei    = (const int*)d_in[6];
    const int*   net    = (const int*)d_in[7];
    float* out = (float*)d_out;

    // workspace: Wh 64KB | A8 3.2MB
    char* basep = (char*)d_ws;
    unsigned short* Wh = (unsigned short*)basep;
    unsigned char*  A8 = (unsigned char*)(basep + 65536);

    (void)hipMemsetAsync(out, 0, sizeof(float), stream);
    prep_kernel<<<512, 256, 0, stream>>>(assign, icl, la, Wh, A8);
    edge_kernel<<<2 * NBLK, 256, 0, stream>>>(A8, Wh, ab, ei, et, nei, net, out);
}

// Round 9
// 172.114 us; speedup vs baseline: 1.2781x; 1.0577x over previous
//
#include <hip/hip_runtime.h>
#include <hip/hip_bf16.h>
#include <math.h>

#define E_EDGES 1000000
#define N_NODES 50000
#define N_C     64
#define N_REL   8
#define CHB     1024        // edges per block
#define CAP     224         // per-rel LDS capacity (E=128, sigma~10.6 -> 9 sigma)
#define NBLK    977         // ceil(1e6 / 1024)

typedef _Float16 half2v __attribute__((ext_vector_type(2)));
typedef _Float16 half8  __attribute__((ext_vector_type(8)));
typedef __attribute__((ext_vector_type(4))) float floatx4;
typedef __attribute__((ext_vector_type(2))) float floatx2;

static __device__ __forceinline__ unsigned short f2h_bits(float x) {
    _Float16 h = (_Float16)x;
    return __builtin_bit_cast(unsigned short, h);
}

// pack 4 fp32 -> 4 fp8 e4m3 (RNE); byte j = element j
static __device__ __forceinline__ unsigned pk4_fp8(float a, float b, float c, float d) {
    unsigned w = 0;
    w = __builtin_amdgcn_cvt_pk_fp8_f32(a, b, w, false);
    w = __builtin_amdgcn_cvt_pk_fp8_f32(c, d, w, true);
    return w;
}

// decode 8 fp8 bytes -> half8 (fp8 exact in f16)
static __device__ __forceinline__ half8 fp8x8_h8(unsigned lo, unsigned hi) {
    floatx2 f0 = __builtin_amdgcn_cvt_pk_f32_fp8((int)lo, false);
    floatx2 f1 = __builtin_amdgcn_cvt_pk_f32_fp8((int)lo, true);
    floatx2 f2 = __builtin_amdgcn_cvt_pk_f32_fp8((int)hi, false);
    floatx2 f3 = __builtin_amdgcn_cvt_pk_f32_fp8((int)hi, true);
    half2v h0 = __builtin_bit_cast(half2v, __builtin_amdgcn_cvt_pkrtz(f0.x, f0.y));
    half2v h1 = __builtin_bit_cast(half2v, __builtin_amdgcn_cvt_pkrtz(f1.x, f1.y));
    half2v h2 = __builtin_bit_cast(half2v, __builtin_amdgcn_cvt_pkrtz(f2.x, f2.y));
    half2v h3 = __builtin_bit_cast(half2v, __builtin_amdgcn_cvt_pkrtz(f3.x, f3.y));
    half8 h;
    h[0] = h0[0]; h[1] = h0[1]; h[2] = h1[0]; h[3] = h1[1];
    h[4] = h2[0]; h[5] = h2[1]; h[6] = h3[0]; h[7] = h3[1];
    return h;
}

// Kernel 1: W -> f16 [512][64]; assignments -> TWO permuted fp8 arrays:
//   AP8 (B-operand): row byte p = quad*16 + kt*8 + j  holds elem k = kt*32 + quad*8 + j
//   AS8 (src-dot):   row byte p = quad*16 + mt*4 + j  holds elem m = mt*16 + quad*4 + j
// so each MFMA lane gathers exactly one 16B chunk per row. Also zeroes out.
__global__ __launch_bounds__(256) void prep_kernel(
    const float* __restrict__ assign,
    const float* __restrict__ icl,
    const float* __restrict__ la,
    unsigned short* __restrict__ Wh,
    unsigned char*  __restrict__ AP8,
    unsigned char*  __restrict__ AS8,
    float* __restrict__ out)
{
    int tid = blockIdx.x * blockDim.x + threadIdx.x;
    int nth = gridDim.x * blockDim.x;
    if (tid == 0) out[0] = 0.0f;

    for (int i = tid; i < N_REL * N_C * N_C; i += nth) {
        float w = 1.0f / (1.0f + __expf(-icl[i]));
        float g = 1.0f / (1.0f + __expf(-la[i])) * 1.2f - 0.1f;
        g = fminf(fmaxf(g, 0.0f), 1.0f);
        Wh[i] = f2h_bits(w * g);
    }

    // one thread per node row
    for (int n = tid; n < N_NODES; n += nth) {
        const float4* a4 = (const float4*)(assign + (size_t)n * N_C);
        unsigned w[16];
        #pragma unroll
        for (int i = 0; i < 16; ++i) {
            float4 v = a4[i];
            w[i] = pk4_fp8(v.x, v.y, v.z, v.w);   // w[i] = elems 4i..4i+3
        }
        // AP8: dword[quad*4 + kt*2 + jh] = w[kt*8 + quad*2 + jh]
        uint4* ap = (uint4*)(AP8 + (size_t)n * N_C);
        #pragma unroll
        for (int quad = 0; quad < 4; ++quad) {
            uint4 o;
            o.x = w[0 * 8 + quad * 2 + 0];
            o.y = w[0 * 8 + quad * 2 + 1];
            o.z = w[1 * 8 + quad * 2 + 0];
            o.w = w[1 * 8 + quad * 2 + 1];
            ap[quad] = o;
        }
        // AS8: dword[quad*4 + mt] = w[mt*4 + quad]
        uint4* as = (uint4*)(AS8 + (size_t)n * N_C);
        #pragma unroll
        for (int quad = 0; quad < 4; ++quad) {
            uint4 o;
            o.x = w[0 * 4 + quad];
            o.y = w[1 * 4 + quad];
            o.z = w[2 * 4 + quad];
            o.w = w[3 * 4 + quad];
            as[quad] = o;
        }
    }
}

// Kernel 2: fused edge pass. Per block: bin CHB edges by relation in LDS,
// then per relation MFMA-batch 16 edges/wave:
//   P[64 x 16] = W_r (A-op, stationary) x dst-vecs (B-op, one 16B fp8 gather)
//   logit_n = sum_m src[m][n] * P[m][n]   (one 16B fp8 src gather)
__global__ __launch_bounds__(256, 6) void edge_kernel(
    const unsigned char* __restrict__ AP8,
    const unsigned char* __restrict__ AS8,
    const unsigned short* __restrict__ Wh,
    const float* __restrict__ absent_bias,
    const int* __restrict__ ei, const int* __restrict__ et,
    const int* __restrict__ nei, const int* __restrict__ net,
    float* __restrict__ out)
{
    __shared__ unsigned list[N_REL * CAP];
    __shared__ unsigned cnt[N_REL];
    __shared__ float red[4];
    if (threadIdx.x < N_REL) cnt[threadIdx.x] = 0u;
    __syncthreads();

    int blk = blockIdx.x;
    bool isneg = blk >= NBLK;
    int lb = isneg ? blk - NBLK : blk;
    const int* Es = isneg ? nei : ei;
    const int* Et = isneg ? net : et;
    float sign = isneg ? 1.0f : -1.0f;
    int base = lb * CHB;
    int elim = min(base + CHB, E_EDGES);

    // Phase 1: LDS relation binning (coalesced edge reads)
    for (int e = base + threadIdx.x; e < elim; e += 256) {
        int s = Es[e];
        int d = Es[E_EDGES + e];
        int r = Et[e];
        unsigned rank = atomicAdd(&cnt[r], 1u);
        if (rank < CAP) list[r * CAP + rank] = (unsigned)s | ((unsigned)d << 16);
    }
    __syncthreads();

    int lane = threadIdx.x & 63;
    int wid  = threadIdx.x >> 6;
    int n16  = lane & 15;
    int quad = lane >> 4;
    float loss = 0.0f;

    for (int r = 0; r < N_REL; ++r) {
        int n_r = min((int)cnt[r], CAP);
        if (n_r == 0) continue;
        float bias = absent_bias[r];
        // stationary A-operand: W_r rows (out-dim tile mt, k-tile kt)
        half8 wf[4][2];
        #pragma unroll
        for (int mt = 0; mt < 4; ++mt)
            #pragma unroll
            for (int kt = 0; kt < 2; ++kt)
                wf[mt][kt] = *(const half8*)(Wh + ((r * 64 + mt * 16 + n16) << 6) + kt * 32 + quad * 8);

        for (int g = wid; g * 16 < n_r; g += 4) {
            int idx = g * 16 + n16;
            bool valid = idx < n_r;
            unsigned rec = list[r * CAP + (valid ? idx : 0)];
            int src = rec & 0xFFFF;
            int dst = rec >> 16;
            // one 16B gather each for dst (B-op) and src (P-dot)
            uint4 D = *(const uint4*)(AP8 + ((size_t)dst << 6) + quad * 16);
            uint4 S = *(const uint4*)(AS8 + ((size_t)src << 6) + quad * 16);
            half8 b0 = fp8x8_h8(D.x, D.y);
            half8 b1 = fp8x8_h8(D.z, D.w);
            floatx4 ac[4];
            #pragma unroll
            for (int mt = 0; mt < 4; ++mt) {
                floatx4 z = {0.0f, 0.0f, 0.0f, 0.0f};
                z = __builtin_amdgcn_mfma_f32_16x16x32_f16(wf[mt][0], b0, z, 0, 0, 0);
                ac[mt] = __builtin_amdgcn_mfma_f32_16x16x32_f16(wf[mt][1], b1, z, 0, 0, 0);
            }
            // lane holds P[m = mt*16 + quad*4 + reg][n16]; S dword mt = those 4 m's
            unsigned sw[4] = {S.x, S.y, S.z, S.w};
            float dot = 0.0f;
            #pragma unroll
            for (int mt = 0; mt < 4; ++mt) {
                floatx2 lo = __builtin_amdgcn_cvt_pk_f32_fp8((int)sw[mt], false);
                floatx2 hi = __builtin_amdgcn_cvt_pk_f32_fp8((int)sw[mt], true);
                dot = fmaf(lo.x, ac[mt][0], dot);
                dot = fmaf(lo.y, ac[mt][1], dot);
                dot = fmaf(hi.x, ac[mt][2], dot);
                dot = fmaf(hi.y, ac[mt][3], dot);
            }
            dot += __shfl_xor(dot, 16);
            dot += __shfl_xor(dot, 32);
            if (quad == 0 && valid) {
                float x = sign * (dot + bias);
                loss += fmaxf(x, 0.0f) + __logf(1.0f + __expf(-fabsf(x)));
            }
        }
    }

    loss += __shfl_xor(loss, 1);
    loss += __shfl_xor(loss, 2);
    loss += __shfl_xor(loss, 4);
    loss += __shfl_xor(loss, 8);
    loss += __shfl_xor(loss, 16);
    loss += __shfl_xor(loss, 32);
    if (lane == 0) red[wid] = loss;
    __syncthreads();
    if (threadIdx.x == 0)
        atomicAdd(out, (red[0] + red[1] + red[2] + red[3]) * (1.0f / (float)E_EDGES));
}

extern "C" void kernel_launch(void* const* d_in, const int* in_sizes, int n_in,
                              void* d_out, int out_size, void* d_ws, size_t ws_size,
                              hipStream_t stream) {
    const float* assign = (const float*)d_in[0];
    const float* icl    = (const float*)d_in[1];
    const float* la     = (const float*)d_in[2];
    const float* ab     = (const float*)d_in[3];
    const int*   ei     = (const int*)d_in[4];
    const int*   et     = (const int*)d_in[5];
    const int*   nei    = (const int*)d_in[6];
    const int*   net    = (const int*)d_in[7];
    float* out = (float*)d_out;

    // workspace: Wh 64KB | AP8 3.2MB | AS8 3.2MB
    char* basep = (char*)d_ws;
    unsigned short* Wh  = (unsigned short*)basep;
    unsigned char*  AP8 = (unsigned char*)(basep + 65536);
    unsigned char*  AS8 = (unsigned char*)(basep + 65536 + (size_t)N_NODES * N_C);

    prep_kernel<<<256, 256, 0, stream>>>(assign, icl, la, Wh, AP8, AS8, out);
    edge_kernel<<<2 * NBLK, 256, 0, stream>>>(AP8, AS8, Wh, ab, ei, et, nei, net, out);
}